// Round 11
// baseline (396.838 us; speedup 1.0000x reference)
//
#include <hip/hip_runtime.h>
#include <hip/hip_bf16.h>

#define N_NODES 100000
#define N_EDGES 800000
#define K_DIM 256
#define N_DIM 256

typedef __attribute__((ext_vector_type(8)))  short  bf16x8;   // 8 bf16 (4 VGPR)
typedef __attribute__((ext_vector_type(4)))  short  bf16x4;   // 4 bf16 (2 VGPR)
typedef __attribute__((ext_vector_type(4)))  float  f32x4;

__device__ short g_Wt[K_DIM * N_DIM];   // Wt[n][k] = bf16(W[k][n]), 128 KiB
__device__ int   g_bsums[512];
__device__ int   g_boff[512];

static __device__ inline short f32_to_bf16s(float f) {
    __bf16 h = (__bf16)f;                       // RNE convert
    return __builtin_bit_cast(short, h);
}
static __device__ inline float bf16s_to_f32(short s) {
    unsigned int u = ((unsigned int)(unsigned short)s) << 16;
    return __uint_as_float(u);
}

// ---------------------------------------------------------------------------
// Fused: blocks [0,256) transpose+convert W; blocks [256,...) count edges.
// ---------------------------------------------------------------------------
__global__ __launch_bounds__(256) void convert_count_kernel(const float* __restrict__ W,
                                                            const int* __restrict__ edst,
                                                            int* __restrict__ counts,
                                                            int E) {
    const int b = blockIdx.x;
    if (b < N_DIM) {
        const int n = b;
        const int k = threadIdx.x;
        g_Wt[n * K_DIM + k] = f32_to_bf16s(W[(size_t)k * N_DIM + n]);
    } else {
        const int e = (b - N_DIM) * 256 + threadIdx.x;
        if (e < E) atomicAdd(&counts[edst[e]], 1);
    }
}

// ---------------------------------------------------------------------------
// MFMA GEMM, whole-K single-barrier: S(bf16) = X @ W, bf16 16x16x32, fp32 acc.
// Block: 256 thr / 4 waves. BM=64 rows, full N=256 (wave w -> cols w*64..+63).
// A panel (64 rows x 256 k) staged ONCE as bf16 into 32 KB LDS:
//   reg-staged (coalesced 32B f32 loads -> cvt -> swizzled ds_write_b128).
//   16B-chunk c (0..31 per 512B row) stored at c' = (c&24)|((c^row)&7);
//   read applies the same XOR (both-sides rule). One __syncthreads total.
// Inner loop: ds_read_b128 IS the A-frag (no cvt), B direct from L2 g_Wt.
// C/D: col = lane&15, row = (lane>>4)*4 + reg   [m89-verified]
// ---------------------------------------------------------------------------
#define GBM 64

__global__ __launch_bounds__(256) void mfma_gemm_kernel(const float* __restrict__ X,
                                                        short* __restrict__ Sb,
                                                        int M) {
    __shared__ short A_lds[GBM * K_DIM];   // 32 KB bf16

    const int tid  = threadIdx.x;
    const int wave = tid >> 6;
    const int lane = tid & 63;
    const int r    = lane & 15;
    const int kg   = lane >> 4;
    const int m0   = blockIdx.x * GBM;
    const int wc   = wave * 64;

    // ---- Stage whole A panel: 2048 16B-chunks, 8 per thread ----
    #pragma unroll
    for (int p = 0; p < 8; ++p) {
        const int d   = p * 256 + tid;       // chunk id 0..2047
        const int row = d >> 5;              // 0..63
        const int c   = d & 31;              // logical 16B chunk in row
        const int cp  = (c & 24) | ((c ^ row) & 7);
        int gr = m0 + row;
        gr = gr < M ? gr : (M - 1);
        const float* gp = X + (size_t)gr * K_DIM + c * 8;
        f32x4 lo = *reinterpret_cast<const f32x4*>(gp);
        f32x4 hi = *reinterpret_cast<const f32x4*>(gp + 4);
        bf16x8 v;
        v[0] = f32_to_bf16s(lo[0]); v[1] = f32_to_bf16s(lo[1]);
        v[2] = f32_to_bf16s(lo[2]); v[3] = f32_to_bf16s(lo[3]);
        v[4] = f32_to_bf16s(hi[0]); v[5] = f32_to_bf16s(hi[1]);
        v[6] = f32_to_bf16s(hi[2]); v[7] = f32_to_bf16s(hi[3]);
        *reinterpret_cast<bf16x8*>(&A_lds[row * K_DIM + cp * 8]) = v;
    }
    __syncthreads();   // the ONLY barrier

    f32x4 acc[4][4];
    #pragma unroll
    for (int i = 0; i < 4; ++i)
        #pragma unroll
        for (int j = 0; j < 4; ++j)
            acc[i][j] = (f32x4)0.f;

    #pragma unroll
    for (int t = 0; t < K_DIM / 32; ++t) {
        const int k0 = t * 32;

        bf16x8 a[4], b[4];
        #pragma unroll
        for (int mi = 0; mi < 4; ++mi) {
            const int rl = mi * 16 + r;
            const int c  = 4 * t + kg;                     // logical chunk
            const int cp = (c & 24) | ((c ^ rl) & 7);      // swizzled
            a[mi] = *reinterpret_cast<const bf16x8*>(&A_lds[rl * K_DIM + cp * 8]);
        }
        #pragma unroll
        for (int ni = 0; ni < 4; ++ni) {
            const short* q = g_Wt + (size_t)(wc + ni * 16 + r) * K_DIM + k0 + kg * 8;
            b[ni] = *reinterpret_cast<const bf16x8*>(q);
        }
        #pragma unroll
        for (int mi = 0; mi < 4; ++mi)
            #pragma unroll
            for (int ni = 0; ni < 4; ++ni)
                acc[mi][ni] = __builtin_amdgcn_mfma_f32_16x16x32_bf16(a[mi], b[ni], acc[mi][ni], 0, 0, 0);
    }

    #pragma unroll
    for (int mi = 0; mi < 4; ++mi) {
        #pragma unroll
        for (int reg = 0; reg < 4; ++reg) {
            const int row = m0 + mi * 16 + kg * 4 + reg;
            if (row < M) {
                #pragma unroll
                for (int ni = 0; ni < 4; ++ni)
                    Sb[(size_t)row * N_DIM + wc + ni * 16 + r] = f32_to_bf16s(acc[mi][ni][reg]);
            }
        }
    }
}

// ---------------------------------------------------------------------------
// Scan (3-stage) over counts -> offsets (+ cursor seed)
// ---------------------------------------------------------------------------
#define SCAN_NB ((N_NODES + 255) / 256)   // 391

__global__ __launch_bounds__(256) void scan1_kernel(const int* __restrict__ counts) {
    __shared__ int wsum[4];
    const int i = blockIdx.x * 256 + threadIdx.x;
    int v = (i < N_NODES) ? counts[i] : 0;
    #pragma unroll
    for (int st = 32; st > 0; st >>= 1) v += __shfl_down(v, st, 64);
    if ((threadIdx.x & 63) == 0) wsum[threadIdx.x >> 6] = v;
    __syncthreads();
    if (threadIdx.x == 0) g_bsums[blockIdx.x] = wsum[0] + wsum[1] + wsum[2] + wsum[3];
}

__global__ __launch_bounds__(512) void scan2_kernel() {
    __shared__ int s[512];
    const int t = threadIdx.x;
    int v = (t < SCAN_NB) ? g_bsums[t] : 0;
    s[t] = v;
    __syncthreads();
    for (int st = 1; st < 512; st <<= 1) {
        int u = (t >= st) ? s[t - st] : 0;
        __syncthreads();
        s[t] += u;
        __syncthreads();
    }
    g_boff[t] = s[t] - v;   // exclusive prefix
}

__global__ __launch_bounds__(256) void scan3_kernel(const int* __restrict__ counts,
                                                    int* __restrict__ offsets,
                                                    int* __restrict__ cursor) {
    __shared__ int s[256];
    const int t = threadIdx.x;
    const int i = blockIdx.x * 256 + t;
    int v = (i < N_NODES) ? counts[i] : 0;
    s[t] = v;
    __syncthreads();
    for (int st = 1; st < 256; st <<= 1) {
        int u = (t >= st) ? s[t - st] : 0;
        __syncthreads();
        s[t] += u;
        __syncthreads();
    }
    if (i < N_NODES) {
        int inc = g_boff[blockIdx.x] + s[t];
        offsets[i + 1] = inc;
        cursor[i]      = inc - v;
    }
    if (i == 0) offsets[0] = 0;
}

__global__ __launch_bounds__(256) void fill_kernel(const int* __restrict__ esrc,
                                                   const int* __restrict__ edst,
                                                   const float* __restrict__ ew,
                                                   int* __restrict__ cursor,
                                                   int2* __restrict__ csr, int E) {
    int e = blockIdx.x * 256 + threadIdx.x;
    if (e >= E) return;
    int pos = atomicAdd(&cursor[edst[e]], 1);
    csr[pos] = make_int2(esrc[e], __float_as_int(ew[e]));
}

// ---------------------------------------------------------------------------
// Gather: one wave per dst node. supp is bf16 (512 B/row, 8 B/lane).
// Nontemporal csr loads / out stores (touch-once data; keep L2 for supp).
// ---------------------------------------------------------------------------
__global__ __launch_bounds__(256) void gather_kernel(const short* __restrict__ Sb,
                                                     const float* __restrict__ bias,
                                                     const int* __restrict__ offsets,
                                                     const long long* __restrict__ csr,
                                                     float* __restrict__ out) {
    const int tid  = threadIdx.x;
    const int node = blockIdx.x * 4 + (tid >> 6);
    if (node >= N_NODES) return;
    const int lane = tid & 63;

    const int row = offsets[node];
    const int end = offsets[node + 1];

    f32x4 acc = *reinterpret_cast<const f32x4*>(bias + lane * 4);

    int j = row;
    for (; j + 2 <= end; j += 2) {
        const long long q0 = __builtin_nontemporal_load(&csr[j]);
        const long long q1 = __builtin_nontemporal_load(&csr[j + 1]);
        const int   s0 = (int)(unsigned int)(q0 & 0xffffffffll);
        const int   s1 = (int)(unsigned int)(q1 & 0xffffffffll);
        const float w0 = __int_as_float((int)(q0 >> 32));
        const float w1 = __int_as_float((int)(q1 >> 32));
        const bf16x4 v0 = *reinterpret_cast<const bf16x4*>(Sb + (size_t)s0 * N_DIM + lane * 4);
        const bf16x4 v1 = *reinterpret_cast<const bf16x4*>(Sb + (size_t)s1 * N_DIM + lane * 4);
        #pragma unroll
        for (int c = 0; c < 4; ++c)
            acc[c] += bf16s_to_f32(v0[c]) * w0 + bf16s_to_f32(v1[c]) * w1;
    }
    if (j < end) {
        const long long q = __builtin_nontemporal_load(&csr[j]);
        const int   s = (int)(unsigned int)(q & 0xffffffffll);
        const float w = __int_as_float((int)(q >> 32));
        const bf16x4 v = *reinterpret_cast<const bf16x4*>(Sb + (size_t)s * N_DIM + lane * 4);
        #pragma unroll
        for (int c = 0; c < 4; ++c)
            acc[c] += bf16s_to_f32(v[c]) * w;
    }

    __builtin_nontemporal_store(acc, reinterpret_cast<f32x4*>(out + (size_t)node * N_DIM + lane * 4));
}

// ---------------------------------------------------------------------------
// Fallback (ws too small): atomic scatter path on bf16 supp
// ---------------------------------------------------------------------------
__global__ __launch_bounds__(256) void init_out_kernel(float* __restrict__ out,
                                                       const float* __restrict__ bias,
                                                       int total) {
    int i = blockIdx.x * 256 + threadIdx.x;
    if (i < total) out[i] = bias[i & (N_DIM - 1)];
}

__global__ __launch_bounds__(256) void scatter_kernel(const short* __restrict__ Sb,
                                                      const float* __restrict__ ew,
                                                      const int* __restrict__ esrc,
                                                      const int* __restrict__ edst,
                                                      float* __restrict__ out, int E) {
    const int tid  = threadIdx.x;
    const int e    = blockIdx.x * 4 + (tid >> 6);
    if (e >= E) return;
    const int lane = tid & 63;
    const int   s = esrc[e];
    const int   d = edst[e];
    const float w = ew[e];
    const bf16x4 v = *reinterpret_cast<const bf16x4*>(Sb + (size_t)s * N_DIM + lane * 4);
    float* o = out + (size_t)d * N_DIM + lane * 4;
    unsafeAtomicAdd(o + 0, bf16s_to_f32(v[0]) * w);
    unsafeAtomicAdd(o + 1, bf16s_to_f32(v[1]) * w);
    unsafeAtomicAdd(o + 2, bf16s_to_f32(v[2]) * w);
    unsafeAtomicAdd(o + 3, bf16s_to_f32(v[3]) * w);
}

// ---------------------------------------------------------------------------
extern "C" void kernel_launch(void* const* d_in, const int* in_sizes, int n_in,
                              void* d_out, int out_size, void* d_ws, size_t ws_size,
                              hipStream_t stream) {
    const float* x      = (const float*)d_in[0];
    const float* weight = (const float*)d_in[1];
    const float* bias   = (const float*)d_in[2];
    const float* ew     = (const float*)d_in[3];
    const int*   esrc   = (const int*)d_in[4];
    const int*   edst   = (const int*)d_in[5];
    float*       out    = (float*)d_out;

    // Workspace layout
    char*  ws     = (char*)d_ws;
    const size_t SUPP_B = ((size_t)N_NODES * N_DIM * 2 + 255) & ~(size_t)255;  // bf16 supp
    const size_t CNT_B  = (size_t)N_NODES * 4;
    const size_t OFF_B  = ((size_t)(N_NODES + 1) * 4 + 15) & ~(size_t)15;
    const size_t CSR_B  = (size_t)N_EDGES * 8;

    short* supp    = (short*)(ws);
    int*   counts  = (int*)  (ws + SUPP_B);
    int*   cursor  = (int*)  (ws + SUPP_B + CNT_B);
    int*   offsets = (int*)  (ws + SUPP_B + 2 * CNT_B);
    int2*  csr     = (int2*) (ws + SUPP_B + 2 * CNT_B + OFF_B);
    const size_t NEEDED = SUPP_B + 2 * CNT_B + OFF_B + CSR_B;

    const int EDGE_NB = (N_EDGES + 255) / 256;

    if (ws_size >= NEEDED) {
        // 0) zero counts, then fused {Wt convert | edge count}
        (void)hipMemsetAsync(counts, 0, CNT_B, stream);
        convert_count_kernel<<<N_DIM + EDGE_NB, 256, 0, stream>>>(weight, edst, counts, N_EDGES);
        // 1) supp(bf16) = x @ W via MFMA (whole-K LDS, single barrier)
        mfma_gemm_kernel<<<(N_NODES + GBM - 1) / GBM, 256, 0, stream>>>(x, supp, N_NODES);
        // 2) offsets/cursor from counts
        scan1_kernel<<<SCAN_NB, 256, 0, stream>>>(counts);
        scan2_kernel<<<1, 512, 0, stream>>>();
        scan3_kernel<<<SCAN_NB, 256, 0, stream>>>(counts, offsets, cursor);
        // 3) CSR fill, then gather+bias
        fill_kernel<<<EDGE_NB, 256, 0, stream>>>(esrc, edst, ew, cursor, csr, N_EDGES);
        gather_kernel<<<(N_NODES + 3) / 4, 256, 0, stream>>>(supp, bias, offsets,
                                                             (const long long*)csr, out);
    } else {
        convert_count_kernel<<<N_DIM, 256, 0, stream>>>(weight, edst, /*unused*/ (int*)d_ws, 0);
        mfma_gemm_kernel<<<(N_NODES + GBM - 1) / GBM, 256, 0, stream>>>(x, supp, N_NODES);
        int total = N_NODES * N_DIM;
        init_out_kernel<<<(total + 255) / 256, 256, 0, stream>>>(out, bias, total);
        scatter_kernel<<<(N_EDGES + 3) / 4, 256, 0, stream>>>(supp, ew, esrc, edst, out, N_EDGES);
    }
}